// Round 13
// baseline (3770.191 us; speedup 1.0000x reference)
//
#include <hip/hip_runtime.h>
#include <hip/hip_bf16.h>
#include <cstdio>

// QuantGRU: T=512, B=64, I=H=1024.
// k_gemm_x: x-projections GEMM, B-tile staged via global_load_lds (async).
// k_recurrent v13: persistent 64-WG x 512-thread kernel, TWO batch-row teams
// per WG (groups gA=wg>>4 and gB=gA+4 share the WG's 64-col weight slice --
// weights are batch-independent). Teams are phase-staggered so each team's
// tagged-word mall round-trip hides under the other team's compute.
// h exchange = r6/r10/r12-proven TAGGED WORDS (u32=(bf16<<16)|step, sc0 sc1
// both sides, fire-and-forget store, full-reload cooperative poll).
// Poll traffic unchanged vs r12 (4MB/step); the serialized visibility chain
// (the r12 bottleneck) is overlapped. Poll caps prevent timeouts.

typedef short bf16x8 __attribute__((ext_vector_type(8)));
typedef float f32x4 __attribute__((ext_vector_type(4)));
typedef int i32x4 __attribute__((ext_vector_type(4)));

#define NT 512
#define NB 64
#define NH 1024
#define NBH 65536   // NB*NH

// ws layout (bytes)
#define OFF_HBUF  4096UL                                   // 2 x 64x1024 u32 = 512KB (tagged)
#define OFF_WCAT  (OFF_HBUF + 2UL * NB * NH * 4)           // 3072x1024 bf16 (Wri|Wii|Wni)
#define OFF_WH    (OFF_WCAT + 3UL * NH * NH * 2)           // 3 x 1024x1024 bf16 (Wrh,Wih,Wnh)
#define OFF_GR    (OFF_WH   + 3UL * NH * NH * 2)           // 32768x1024 bf16
#define OFF_GI    (OFF_GR   + (unsigned long)NT * NB * NH * 2)
#define WS_NEED   (OFF_GI   + (unsigned long)NT * NB * NH * 2)   // ~140.6 MB

__device__ __forceinline__ float clampf(float x) { return fminf(fmaxf(x, -1.f), 1.f); }

__device__ __forceinline__ unsigned short f2bf(float x) {
  __hip_bfloat16 h = __float2bfloat16(x);
  union { __hip_bfloat16 h; unsigned short u; } cv;
  cv.h = h;
  return cv.u;
}
__device__ __forceinline__ float bf2f(unsigned short u) {
  return __uint_as_float(((unsigned)u) << 16);
}
__device__ __forceinline__ float frcp(float x) { return __builtin_amdgcn_rcpf(x); }
__device__ __forceinline__ float fsigmoid(float x) { return frcp(1.f + __expf(-x)); }
__device__ __forceinline__ float ftanh(float z) { return 1.f - 2.f * frcp(1.f + __expf(2.f * z)); }

__device__ __forceinline__ i32x4 pack8(float4 v0, float4 v1) {
  i32x4 q;
  q[0] = (int)(f2bf(clampf(v0.x)) | ((unsigned)f2bf(clampf(v0.y)) << 16));
  q[1] = (int)(f2bf(clampf(v0.z)) | ((unsigned)f2bf(clampf(v0.w)) << 16));
  q[2] = (int)(f2bf(clampf(v1.x)) | ((unsigned)f2bf(clampf(v1.y)) << 16));
  q[3] = (int)(f2bf(clampf(v1.z)) | ((unsigned)f2bf(clampf(v1.w)) << 16));
  return q;
}

// async global->LDS 16B
__device__ __forceinline__ void gload_lds16(const void* g, void* l) {
  __builtin_amdgcn_global_load_lds(
      (const __attribute__((address_space(1))) void*)g,
      (__attribute__((address_space(3))) void*)l, 16, 0, 0);
}

// 8x dwordx4 cached loads into asm-pinned regs (no remat possible).
__device__ __forceinline__ void load_frags8(const unsigned short* p, i32x4 a[8]) {
  asm volatile(
      "global_load_dwordx4 %0, %8, off\n\t"
      "global_load_dwordx4 %1, %8, off offset:64\n\t"
      "global_load_dwordx4 %2, %8, off offset:128\n\t"
      "global_load_dwordx4 %3, %8, off offset:192\n\t"
      "global_load_dwordx4 %4, %8, off offset:256\n\t"
      "global_load_dwordx4 %5, %8, off offset:320\n\t"
      "global_load_dwordx4 %6, %8, off offset:384\n\t"
      "global_load_dwordx4 %7, %8, off offset:448\n\t"
      "s_waitcnt vmcnt(0)"
      : "=&v"(a[0]), "=&v"(a[1]), "=&v"(a[2]), "=&v"(a[3]),
        "=&v"(a[4]), "=&v"(a[5]), "=&v"(a[6]), "=&v"(a[7])
      : "v"(p)
      : "memory");
}
// fire-and-forget write-through store (r6-proven visibility path)
__device__ __forceinline__ void store_u32_wt(unsigned int* p, unsigned v) {
  asm volatile("global_store_dword %0, %1, off sc0 sc1" :: "v"(p), "v"(v) : "memory");
}

// ---------------- kernel 0: weights f32 -> bf16 ---------------------------
__global__ void k_convert_weights(const float* __restrict__ wri, const float* __restrict__ wii,
                                  const float* __restrict__ wni, const float* __restrict__ wrh,
                                  const float* __restrict__ wih, const float* __restrict__ wnh,
                                  unsigned short* __restrict__ wcat, unsigned short* __restrict__ wh) {
  const long total = 6L * 1024 * 1024;
  long stride = (long)gridDim.x * blockDim.x * 4;
  for (long i = ((long)blockIdx.x * blockDim.x + threadIdx.x) * 4; i < total; i += stride) {
    int m = (int)(i >> 20);              // which matrix
    long off = i & 1048575L;
    const float* srcs[6] = {wri, wii, wni, wrh, wih, wnh};
    float4 v = *(const float4*)(srcs[m] + off);
    ushort4 o;
    o.x = f2bf(v.x); o.y = f2bf(v.y); o.z = f2bf(v.z); o.w = f2bf(v.w);
    unsigned short* dst = (m < 3) ? (wcat + ((long)m << 20) + off)
                                  : (wh + ((long)(m - 3) << 20) + off);
    *(ushort4*)dst = o;
  }
}

// ---------------- kernel 1: input projections GEMM ------------------------
#define BK 64
__launch_bounds__(256)
__global__ void k_gemm_x(const float* __restrict__ A,              // X f32 [32768][1024]
                         const unsigned short* __restrict__ Bw,    // Wcat bf16 [3072][1024]
                         unsigned short* __restrict__ gr, unsigned short* __restrict__ gi,
                         float* __restrict__ gni,                  // = d_out plane [32768][1024]
                         const float* __restrict__ br, const float* __restrict__ bi,
                         const float* __restrict__ bni) {
  __shared__ unsigned short As[128 * BK];
  __shared__ unsigned short Bs[128 * BK];

  int bid = blockIdx.x;
  int bm = bid / 24, bn = bid % 24;
  int tid = threadIdx.x;
  int lane = tid & 63, w = tid >> 6;
  int wm = w >> 1, wn = w & 1;

  long arow0 = (long)bm * 128;
  long brow0 = (long)bn * 128;

  f32x4 acc[4][4] = {};

  for (int kt = 0; kt < 1024; kt += BK) {
    __syncthreads();
#pragma unroll
    for (int it = 0; it < 4; ++it) {
      int f = it * 2048 + tid * 8;
      int r = f >> 6, c = f & 63;
      // B: async direct-to-LDS 16B (bf16, no transform)
      gload_lds16(Bw + (brow0 + r) * 1024 + kt + c, &Bs[f]);
      // A: f32 -> clamp -> bf16 pack (register path)
      const float* ap = A + (arow0 + r) * 1024 + kt + c;
      float4 v0 = *(const float4*)ap;
      float4 v1 = *(const float4*)(ap + 4);
      *(i32x4*)(&As[f]) = pack8(v0, v1);
    }
    __syncthreads();   // drains vmcnt (async B) + lgkm (A ds_writes)
#pragma unroll
    for (int ks = 0; ks < 2; ++ks) {
      bf16x8 a[4], b[4];
#pragma unroll
      for (int fm = 0; fm < 4; ++fm)
        a[fm] = *(const bf16x8*)(&As[(wm * 64 + fm * 16 + (lane & 15)) * BK + ks * 32 + (lane >> 4) * 8]);
#pragma unroll
      for (int fn = 0; fn < 4; ++fn)
        b[fn] = *(const bf16x8*)(&Bs[(wn * 64 + fn * 16 + (lane & 15)) * BK + ks * 32 + (lane >> 4) * 8]);
#pragma unroll
      for (int fm = 0; fm < 4; ++fm)
#pragma unroll
        for (int fn = 0; fn < 4; ++fn)
          acc[fm][fn] = __builtin_amdgcn_mfma_f32_16x16x32_bf16(a[fm], b[fn], acc[fm][fn], 0, 0, 0);
    }
  }

  int g = bn >> 3;  // 0:r 1:i 2:ni (uniform per block)
  const float* bias = (g == 0) ? br : (g == 1) ? bi : bni;
#pragma unroll
  for (int fm = 0; fm < 4; ++fm) {
    long m = arow0 + wm * 64 + fm * 16 + (lane >> 4) * 4;
#pragma unroll
    for (int fn = 0; fn < 4; ++fn) {
      long n = brow0 + wn * 64 + fn * 16 + (lane & 15);
      long colg = n & 1023;
      float bv = bias[colg];
#pragma unroll
      for (int r2 = 0; r2 < 4; ++r2) {
        float v = acc[fm][fn][r2] + bv;
        long idx = (m + r2) * 1024 + colg;
        if (g == 0)      gr[idx] = f2bf(v);
        else if (g == 1) gi[idx] = f2bf(v);
        else             gni[idx] = clampf(v);   // pre-clamped ni (includes bias)
      }
    }
  }
}

// ---------------- kernel 2: persistent recurrence (v13: two-team) ---------
// 64 WGs x 512 threads (8 waves = 2 col-halves x 4 K-quarters).
// gA = wg>>4 (0..3), gB = gA+4, slot = wg&15 (64 hidden cols). Both teams
// share the pinned weight slice. Schedule staggers each team's exchange
// under the other team's compute.
__launch_bounds__(512, 1)
__global__ void k_recurrent(const unsigned short* __restrict__ wh,   // [3][1024][1024] bf16
                            const unsigned short* __restrict__ gr,
                            const unsigned short* __restrict__ gi,
                            const float* __restrict__ state,
                            const float* __restrict__ bias_nh,
                            unsigned int* __restrict__ hbuf,         // [2][64][1024] u32 tagged
                            float* __restrict__ out) {               // [512][64][1024] + [64][1024]
  __shared__ unsigned short h_ldsA[8 * 1024];          // 16KB, XOR-swizzled
  __shared__ unsigned short h_ldsB[8 * 1024];          // 16KB
  __shared__ float redA[4][3][2][2][8][16];            // 24KB
  __shared__ float redB[4][3][2][2][8][16];            // 24KB

  int tid = threadIdx.x;
  int lane = tid & 63, w = tid >> 6;      // w 0..7
  int ch = w >> 2;                        // col-half 0..1
  int kw = w & 3;                         // K-quarter 0..3
  int wg = blockIdx.x;
  int gA = wg >> 4;       // 0..3  -> batch rows gA*8..+8
  int gB = gA + 4;        // 4..7
  int slot = wg & 15;     // hidden cols slot*64..+64

  // ---- pinned weights (shared by both teams): 192 VGPRs ----
  int klane = (lane >> 4) * 8;
  int k0 = kw * 256;
  i32x4 wfi[3][2][8];
#pragma unroll
  for (int g2 = 0; g2 < 3; ++g2)
#pragma unroll
    for (int n2 = 0; n2 < 2; ++n2) {
      int col = slot * 64 + ch * 32 + n2 * 16 + (lane & 15);
      load_frags8(wh + ((long)g2 << 20) + (long)col * 1024 + k0 + klane, wfi[g2][n2]);
    }

  // ---- per-thread pointwise cells: row=tid>>6 (0..7), col=tid&63 ----
  int row = tid >> 6, col = tid & 63;
  long cellA = (long)(gA * 8 + row) * 1024 + slot * 64 + col;
  long cellB = (long)(gB * 8 + row) * 1024 + slot * 64 + col;
  float hA = clampf(state[cellA]);
  float hB = clampf(state[cellB]);
  float bnh = bias_nh[slot * 64 + col];

  // ---- t=0 staging from clamp(state) into both LDS buffers ----
#pragma unroll
  for (int c = 0; c < 4; ++c) {
    int n = c * 512 + tid;                    // 4-cell chunk id (0..2047)
    int r8 = n >> 8;                          // row 0..7
    int coli = (n * 4) & 1023;
    int flat = n * 8;
    int swz = flat ^ (r8 << 4);
    {
      const float* sp = state + (long)(gA * 8 + r8) * 1024 + coli;
      float4 v = *(const float4*)sp;
      int2 pv;
      pv.x = (int)(f2bf(clampf(v.x)) | ((unsigned)f2bf(clampf(v.y)) << 16));
      pv.y = (int)(f2bf(clampf(v.z)) | ((unsigned)f2bf(clampf(v.w)) << 16));
      *(int2*)((char*)h_ldsA + swz) = pv;
    }
    {
      const float* sp = state + (long)(gB * 8 + r8) * 1024 + coli;
      float4 v = *(const float4*)sp;
      int2 pv;
      pv.x = (int)(f2bf(clampf(v.x)) | ((unsigned)f2bf(clampf(v.y)) << 16));
      pv.y = (int)(f2bf(clampf(v.z)) | ((unsigned)f2bf(clampf(v.w)) << 16));
      *(int2*)((char*)h_ldsB + swz) = pv;
    }
  }

  // ---- LDS fragment read addressing (M=8: rows duplicated, row = lane&7) ----
  const int rowb = (lane & 7) * 2048;
  const int colb = kw * 512 + ((lane >> 4) * 16);
  const int rsw = (lane & 7) << 4;

  // prefetch t=0 pointwise inputs
  float grvA = bf2f(gr[cellA]), givA = bf2f(gi[cellA]), gnivA = out[cellA];
  float grvB = bf2f(gr[cellB]), givB = bf2f(gi[cellB]), gnivB = out[cellB];

  __syncthreads();

#pragma unroll 1
  for (int t = 0; t < NT; ++t) {
    unsigned tgt = (unsigned)(t + 1);
    long bank = (long)(tgt & 1) * NBH;
    int chc = col >> 5, n2c = (col >> 4) & 1, cc = col & 15;

    // ======== team A: MFMA + stage ========
    {
      f32x4 acc[3][2] = {};
#pragma unroll
      for (int s = 0; s < 8; ++s) {
        bf16x8 a = *(const bf16x8*)((const char*)h_ldsA + rowb + ((colb + s * 64) ^ rsw));
#pragma unroll
        for (int g2 = 0; g2 < 3; ++g2)
#pragma unroll
          for (int n2 = 0; n2 < 2; ++n2)
            acc[g2][n2] = __builtin_amdgcn_mfma_f32_16x16x32_bf16(
                a, __builtin_bit_cast(bf16x8, wfi[g2][n2][s]), acc[g2][n2], 0, 0, 0);
      }
      int rq = lane >> 4;
      if (rq < 2) {
#pragma unroll
        for (int g2 = 0; g2 < 3; ++g2)
#pragma unroll
          for (int n2 = 0; n2 < 2; ++n2)
#pragma unroll
            for (int r = 0; r < 4; ++r)
              redA[kw][g2][n2][ch][rq * 4 + r][lane & 15] = acc[g2][n2][r];
      }
    }
    __syncthreads();                                  // B1

    // ======== team A: reduce + pointwise + tagged store ========
    {
      float pr = redA[0][0][n2c][chc][row][cc] + redA[1][0][n2c][chc][row][cc]
               + redA[2][0][n2c][chc][row][cc] + redA[3][0][n2c][chc][row][cc];
      float pi = redA[0][1][n2c][chc][row][cc] + redA[1][1][n2c][chc][row][cc]
               + redA[2][1][n2c][chc][row][cc] + redA[3][1][n2c][chc][row][cc];
      float pn = redA[0][2][n2c][chc][row][cc] + redA[1][2][n2c][chc][row][cc]
               + redA[2][2][n2c][chc][row][cc] + redA[3][2][n2c][chc][row][cc];
      float rg = fsigmoid(pr + grvA);
      float ig = fsigmoid(pi + givA);
      float ng = ftanh(gnivA + clampf(rg * (pn + bnh)));
      float sx = clampf(hA) - ng;
      float hy = ng + clampf(ig * sx);
      store_u32_wt(hbuf + bank + cellA, ((unsigned)f2bf(hy) << 16) | tgt);
      out[(long)t * NBH + cellA] = hy;
      hA = hy;
      if (t + 1 < NT) {
        long g2ofs = (long)tgt * NBH + cellA;
        grvA = bf2f(gr[g2ofs]); givA = bf2f(gi[g2ofs]); gnivA = out[g2ofs];
      }
    }

    // ======== team B: MFMA + stage ========
    {
      f32x4 acc[3][2] = {};
#pragma unroll
      for (int s = 0; s < 8; ++s) {
        bf16x8 a = *(const bf16x8*)((const char*)h_ldsB + rowb + ((colb + s * 64) ^ rsw));
#pragma unroll
        for (int g2 = 0; g2 < 3; ++g2)
#pragma unroll
          for (int n2 = 0; n2 < 2; ++n2)
            acc[g2][n2] = __builtin_amdgcn_mfma_f32_16x16x32_bf16(
                a, __builtin_bit_cast(bf16x8, wfi[g2][n2][s]), acc[g2][n2], 0, 0, 0);
      }
      int rq = lane >> 4;
      if (rq < 2) {
#pragma unroll
        for (int g2 = 0; g2 < 3; ++g2)
#pragma unroll
          for (int n2 = 0; n2 < 2; ++n2)
#pragma unroll
            for (int r = 0; r < 4; ++r)
              redB[kw][g2][n2][ch][rq * 4 + r][lane & 15] = acc[g2][n2][r];
      }
    }
    __syncthreads();                                  // B2

    // ======== team B: reduce + pointwise + tagged store ========
    {
      float pr = redB[0][0][n2c][chc][row][cc] + redB[1][0][n2c][chc][row][cc]
               + redB[2][0][n2c][chc][row][cc] + redB[3][0][n2c][chc][row][cc];
      float pi = redB[0][1][n2c][chc][row][cc] + redB[1][1][n2c][chc][row][cc]
               + redB[2][1][n2c][chc][row][cc] + redB[3][1][n2c][chc][row][cc];
      float pn = redB[0][2][n2c][chc][row][cc] + redB[1][2][n2c][chc][row][cc]
               + redB[2][2][n2c][chc][row][cc] + redB[3][2][n2c][chc][row][cc];
      float rg = fsigmoid(pr + grvB);
      float ig = fsigmoid(pi + givB);
      float ng = ftanh(gnivB + clampf(rg * (pn + bnh)));
      float sx = clampf(hB) - ng;
      float hy = ng + clampf(ig * sx);
      store_u32_wt(hbuf + bank + cellB, ((unsigned)f2bf(hy) << 16) | tgt);
      out[(long)t * NBH + cellB] = hy;
      hB = hy;
      if (t + 1 < NT) {
        long g2ofs = (long)tgt * NBH + cellB;
        grvB = bf2f(gr[g2ofs]); givB = bf2f(gi[g2ofs]); gnivB = out[g2ofs];
      }
    }

    // ======== exchange: poll+stage A (store_A aged ~B-phase), then B ======
    if (t + 1 < NT) {
      // team A
      {
        const unsigned int* base = hbuf + bank + (long)gA * 8192;
        i32x4 d[4];
        for (unsigned it2 = 0;; ++it2) {
#pragma unroll
          for (int c = 0; c < 4; ++c) {
            const unsigned int* p = base + (long)(c * 512 + tid) * 4;
            asm volatile("global_load_dwordx4 %0, %1, off sc0 sc1"
                         : "=&v"(d[c]) : "v"(p) : "memory");
          }
          asm volatile("s_waitcnt vmcnt(0)" ::: "memory");
          unsigned mn = 0xFFFFFFFFu;
#pragma unroll
          for (int c = 0; c < 4; ++c)
#pragma unroll
            for (int e = 0; e < 4; ++e)
              mn = min(mn, ((unsigned)d[c][e]) & 0xFFFFu);
          if (__all((int)(mn >= tgt)) || it2 > 8192u) break;
          __builtin_amdgcn_s_sleep(1);
        }
#pragma unroll
        for (int c = 0; c < 4; ++c) {
          int n = c * 512 + tid;
          int r8 = n >> 8;
          int flat = n * 8;
          int2 v;
          v.x = (int)__builtin_amdgcn_perm((unsigned)d[c][1], (unsigned)d[c][0], 0x07060302u);
          v.y = (int)__builtin_amdgcn_perm((unsigned)d[c][3], (unsigned)d[c][2], 0x07060302u);
          *(int2*)((char*)h_ldsA + (flat ^ (r8 << 4))) = v;
        }
      }
      // team B
      {
        const unsigned int* base = hbuf + bank + (long)gB * 8192;
        i32x4 d[4];
        for (unsigned it2 = 0;; ++it2) {
#pragma unroll
          for (int c = 0; c < 4; ++c) {
            const unsigned int* p = base + (long)(c * 512 + tid) * 4;
            asm volatile("global_load_dwordx4 %0, %1, off sc0 sc1"
                         : "=&v"(d[c]) : "v"(p) : "memory");
          }
          asm volatile("s_waitcnt vmcnt(0)" ::: "memory");
          unsigned mn = 0xFFFFFFFFu;
#pragma unroll
          for (int c = 0; c < 4; ++c)
#pragma unroll
            for (int e = 0; e < 4; ++e)
              mn = min(mn, ((unsigned)d[c][e]) & 0xFFFFu);
          if (__all((int)(mn >= tgt)) || it2 > 8192u) break;
          __builtin_amdgcn_s_sleep(1);
        }
#pragma unroll
        for (int c = 0; c < 4; ++c) {
          int n = c * 512 + tid;
          int r8 = n >> 8;
          int flat = n * 8;
          int2 v;
          v.x = (int)__builtin_amdgcn_perm((unsigned)d[c][1], (unsigned)d[c][0], 0x07060302u);
          v.y = (int)__builtin_amdgcn_perm((unsigned)d[c][3], (unsigned)d[c][2], 0x07060302u);
          *(int2*)((char*)h_ldsB + (flat ^ (r8 << 4))) = v;
        }
      }
      __syncthreads();                                // B3: both LDS ready
    }
  }

  // last hidden states
  out[(long)NT * NBH + cellA] = hA;
  out[(long)NT * NBH + cellB] = hB;
}

// ---------------------------------------------------------------------------
extern "C" void kernel_launch(void* const* d_in, const int* in_sizes, int n_in,
                              void* d_out, int out_size, void* d_ws, size_t ws_size,
                              hipStream_t stream) {
  const float* inputs = (const float*)d_in[0];
  const float* state  = (const float*)d_in[1];
  const float* wri = (const float*)d_in[2];
  const float* wii = (const float*)d_in[3];
  const float* wni = (const float*)d_in[4];
  const float* wrh = (const float*)d_in[5];
  const float* wih = (const float*)d_in[6];
  const float* wnh = (const float*)d_in[7];
  const float* br  = (const float*)d_in[8];
  const float* bi  = (const float*)d_in[9];
  const float* bni = (const float*)d_in[10];
  const float* bnh = (const float*)d_in[11];

  if (ws_size < WS_NEED) {
    fprintf(stderr, "kernel_launch: ws too small (%zu < %lu)\n", ws_size, WS_NEED);
    return;
  }

  char* ws = (char*)d_ws;
  unsigned int*   hbuf  = (unsigned int*)(ws + OFF_HBUF);
  unsigned short* wcat  = (unsigned short*)(ws + OFF_WCAT);
  unsigned short* whp   = (unsigned short*)(ws + OFF_WH);
  unsigned short* grw   = (unsigned short*)(ws + OFF_GR);
  unsigned short* giw   = (unsigned short*)(ws + OFF_GI);
  float* out = (float*)d_out;

  // zero tag region every launch (stale tags from prior replays must die)
  hipMemsetAsync(ws, 0, OFF_WCAT, stream);
  k_convert_weights<<<512, 256, 0, stream>>>(wri, wii, wni, wrh, wih, wnh, wcat, whp);
  k_gemm_x<<<6144, 256, 0, stream>>>(inputs, wcat, grw, giw, out, br, bi, bni);
  k_recurrent<<<64, 512, 0, stream>>>(whp, grw, giw, state, bnh, hbuf, out);
}

// Round 14
// 1599.183 us; speedup vs baseline: 2.3576x; 2.3576x over previous
//
#include <hip/hip_runtime.h>
#include <hip/hip_bf16.h>
#include <cstdio>

// QuantGRU: T=512, B=64, I=H=1024.
// v14: ONE fused persistent kernel, 256 WGs x 512 threads.
//   WGs 0..127  : r12-verbatim recurrence (8 groups x 8 rows, 16 WGs/group
//                 x 64 cols, 192 asm-pinned weight VGPRs, tagged-word h
//                 exchange: u32=(bf16<<16)|step, sc0 sc1 both sides).
//   WGs 128..255: x-projection GEMM (48 tiles each, 8-wave 128x128 tile,
//                 async global_load_lds B). Epilogue -> sc0 sc1 WT stores,
//                 vmcnt(0)+barrier, then ONE device-scope atomicAdd(cnt[bm]).
// Recurrent gates timestep t on cnt[t>>1]==24 (watermark-cached) and reads
// gr/gi/gni via sc0 sc1 loads. All caps prevent timeouts.

typedef short bf16x8 __attribute__((ext_vector_type(8)));
typedef float f32x4 __attribute__((ext_vector_type(4)));
typedef int i32x4 __attribute__((ext_vector_type(4)));

#define NT 512
#define NB 64
#define NH 1024
#define NBH 65536   // NB*NH

// ws layout (bytes)
#define OFF_CNT   0UL                                      // 256 x 4B tile counters
#define OFF_HBUF  4096UL                                   // 2 x 64x1024 u32 = 512KB (tagged)
#define OFF_WCAT  (OFF_HBUF + 2UL * NB * NH * 4)           // 3072x1024 bf16 (Wri|Wii|Wni)
#define OFF_WH    (OFF_WCAT + 3UL * NH * NH * 2)           // 3 x 1024x1024 bf16 (Wrh,Wih,Wnh)
#define OFF_GR    (OFF_WH   + 3UL * NH * NH * 2)           // 32768x1024 bf16
#define OFF_GI    (OFF_GR   + (unsigned long)NT * NB * NH * 2)
#define WS_NEED   (OFF_GI   + (unsigned long)NT * NB * NH * 2)   // ~140.6 MB

__device__ __forceinline__ float clampf(float x) { return fminf(fmaxf(x, -1.f), 1.f); }

__device__ __forceinline__ unsigned short f2bf(float x) {
  __hip_bfloat16 h = __float2bfloat16(x);
  union { __hip_bfloat16 h; unsigned short u; } cv;
  cv.h = h;
  return cv.u;
}
__device__ __forceinline__ float bf2f(unsigned short u) {
  return __uint_as_float(((unsigned)u) << 16);
}
__device__ __forceinline__ float frcp(float x) { return __builtin_amdgcn_rcpf(x); }
__device__ __forceinline__ float fsigmoid(float x) { return frcp(1.f + __expf(-x)); }
__device__ __forceinline__ float ftanh(float z) { return 1.f - 2.f * frcp(1.f + __expf(2.f * z)); }

__device__ __forceinline__ i32x4 pack8(float4 v0, float4 v1) {
  i32x4 q;
  q[0] = (int)(f2bf(clampf(v0.x)) | ((unsigned)f2bf(clampf(v0.y)) << 16));
  q[1] = (int)(f2bf(clampf(v0.z)) | ((unsigned)f2bf(clampf(v0.w)) << 16));
  q[2] = (int)(f2bf(clampf(v1.x)) | ((unsigned)f2bf(clampf(v1.y)) << 16));
  q[3] = (int)(f2bf(clampf(v1.z)) | ((unsigned)f2bf(clampf(v1.w)) << 16));
  return q;
}

// async global->LDS 16B
__device__ __forceinline__ void gload_lds16(const void* g, void* l) {
  __builtin_amdgcn_global_load_lds(
      (const __attribute__((address_space(1))) void*)g,
      (__attribute__((address_space(3))) void*)l, 16, 0, 0);
}

// 8x dwordx4 cached loads into asm-pinned regs (no remat possible).
__device__ __forceinline__ void load_frags8(const unsigned short* p, i32x4 a[8]) {
  asm volatile(
      "global_load_dwordx4 %0, %8, off\n\t"
      "global_load_dwordx4 %1, %8, off offset:64\n\t"
      "global_load_dwordx4 %2, %8, off offset:128\n\t"
      "global_load_dwordx4 %3, %8, off offset:192\n\t"
      "global_load_dwordx4 %4, %8, off offset:256\n\t"
      "global_load_dwordx4 %5, %8, off offset:320\n\t"
      "global_load_dwordx4 %6, %8, off offset:384\n\t"
      "global_load_dwordx4 %7, %8, off offset:448\n\t"
      "s_waitcnt vmcnt(0)"
      : "=&v"(a[0]), "=&v"(a[1]), "=&v"(a[2]), "=&v"(a[3]),
        "=&v"(a[4]), "=&v"(a[5]), "=&v"(a[6]), "=&v"(a[7])
      : "v"(p)
      : "memory");
}
// fire-and-forget write-through stores (r3/r6-proven visibility path)
__device__ __forceinline__ void store_u32_wt(unsigned int* p, unsigned v) {
  asm volatile("global_store_dword %0, %1, off sc0 sc1" :: "v"(p), "v"(v) : "memory");
}
__device__ __forceinline__ void store_u16_wt(unsigned short* p, unsigned v) {
  asm volatile("global_store_short %0, %1, off sc0 sc1" :: "v"(p), "v"(v) : "memory");
}
__device__ __forceinline__ void store_f32_wt(float* p, float v) {
  asm volatile("global_store_dword %0, %1, off sc0 sc1" :: "v"(p), "v"(v) : "memory");
}
// coherent dword read at the mall
__device__ __forceinline__ unsigned load_u32_mall(const unsigned int* p) {
  unsigned v;
  asm volatile("global_load_dword %0, %1, off sc0 sc1\n\ts_waitcnt vmcnt(0)"
               : "=v"(v) : "v"(p) : "memory");
  return v;
}

// ---------------- kernel 0: weights f32 -> bf16 ---------------------------
__global__ void k_convert_weights(const float* __restrict__ wri, const float* __restrict__ wii,
                                  const float* __restrict__ wni, const float* __restrict__ wrh,
                                  const float* __restrict__ wih, const float* __restrict__ wnh,
                                  unsigned short* __restrict__ wcat, unsigned short* __restrict__ wh) {
  const long total = 6L * 1024 * 1024;
  long stride = (long)gridDim.x * blockDim.x * 4;
  for (long i = ((long)blockIdx.x * blockDim.x + threadIdx.x) * 4; i < total; i += stride) {
    int m = (int)(i >> 20);              // which matrix
    long off = i & 1048575L;
    const float* srcs[6] = {wri, wii, wni, wrh, wih, wnh};
    float4 v = *(const float4*)(srcs[m] + off);
    ushort4 o;
    o.x = f2bf(v.x); o.y = f2bf(v.y); o.z = f2bf(v.z); o.w = f2bf(v.w);
    unsigned short* dst = (m < 3) ? (wcat + ((long)m << 20) + off)
                                  : (wh + ((long)(m - 3) << 20) + off);
    *(ushort4*)dst = o;
  }
}

// ---------------- fused kernel: recurrence + x-GEMM -----------------------
__launch_bounds__(512, 1)
__global__ void k_fused(const unsigned short* __restrict__ wh,     // [3][1024][1024] bf16
                        const unsigned short* __restrict__ wcat,   // [3072][1024] bf16
                        const float* __restrict__ X,               // [32768][1024] f32
                        const float* __restrict__ state,
                        const float* __restrict__ br, const float* __restrict__ bi,
                        const float* __restrict__ bni, const float* __restrict__ bnh,
                        unsigned short* __restrict__ gr, unsigned short* __restrict__ gi,
                        unsigned int* __restrict__ hbuf,           // [2][64][1024] u32 tagged
                        unsigned int* __restrict__ cnt,            // [256] tile counters
                        float* __restrict__ out) {                 // [512][64][1024] + [64][1024]
  __shared__ unsigned short h_lds[8 * 1024];          // 16KB (recurrent)
  __shared__ float red[4][3][2][2][8][16];            // 24KB (recurrent)
  __shared__ unsigned short As[128 * 64];             // 16KB (gemm)
  __shared__ unsigned short Bs[128 * 64];             // 16KB (gemm)

  int tid = threadIdx.x;
  int lane = tid & 63, w = tid >> 6;      // w 0..7
  int wg = blockIdx.x;

  if (wg >= 128) {
    // ================== GEMM role: 48 tiles of 128x128 ==================
    int gw = wg - 128;
    int wm = w >> 2, wn = w & 3;          // 2 x 4 waves, 64x32 per wave
    for (int i = 0; i < 48; ++i) {
      int tile = i * 128 + gw;
      int bm = tile / 24, bn = tile % 24;
      long arow0 = (long)bm * 128;
      long brow0 = (long)bn * 128;
      f32x4 acc[4][2] = {};
      for (int kt = 0; kt < 1024; kt += 64) {
        __syncthreads();
#pragma unroll
        for (int it = 0; it < 2; ++it) {
          int f = it * 4096 + tid * 8;
          int r = f >> 6, c = f & 63;
          gload_lds16(wcat + (brow0 + r) * 1024 + kt + c, &Bs[f]);
          const float* ap = X + (arow0 + r) * 1024 + kt + c;
          float4 v0 = *(const float4*)ap;
          float4 v1 = *(const float4*)(ap + 4);
          *(i32x4*)(&As[f]) = pack8(v0, v1);
        }
        __syncthreads();   // drains vmcnt (async B) + lgkm (A ds_writes)
#pragma unroll
        for (int ks = 0; ks < 2; ++ks) {
          bf16x8 a[4], b[2];
#pragma unroll
          for (int fm = 0; fm < 4; ++fm)
            a[fm] = *(const bf16x8*)(&As[(wm * 64 + fm * 16 + (lane & 15)) * 64 + ks * 32 + (lane >> 4) * 8]);
#pragma unroll
          for (int fn = 0; fn < 2; ++fn)
            b[fn] = *(const bf16x8*)(&Bs[(wn * 32 + fn * 16 + (lane & 15)) * 64 + ks * 32 + (lane >> 4) * 8]);
#pragma unroll
          for (int fm = 0; fm < 4; ++fm)
#pragma unroll
            for (int fn = 0; fn < 2; ++fn)
              acc[fm][fn] = __builtin_amdgcn_mfma_f32_16x16x32_bf16(a[fm], b[fn], acc[fm][fn], 0, 0, 0);
        }
      }
      // epilogue: WT stores to the mall (visible to recurrent role)
      int g = bn >> 3;
      const float* bias = (g == 0) ? br : (g == 1) ? bi : bni;
#pragma unroll
      for (int fm = 0; fm < 4; ++fm) {
        long m = arow0 + wm * 64 + fm * 16 + (lane >> 4) * 4;
#pragma unroll
        for (int fn = 0; fn < 2; ++fn) {
          long n = brow0 + wn * 32 + fn * 16 + (lane & 15);
          long colg = n & 1023;
          float bv = bias[colg];
#pragma unroll
          for (int r2 = 0; r2 < 4; ++r2) {
            float v = acc[fm][fn][r2] + bv;
            long idx = (m + r2) * 1024 + colg;
            if (g == 0)      store_u16_wt(gr + idx, (unsigned)f2bf(v));
            else if (g == 1) store_u16_wt(gi + idx, (unsigned)f2bf(v));
            else             store_f32_wt(out + idx, clampf(v));
          }
        }
      }
      asm volatile("s_waitcnt vmcnt(0)" ::: "memory");   // every wave drains
      __syncthreads();                                    // all waves drained
      if (tid == 0)
        __hip_atomic_fetch_add(&cnt[bm], 1u, __ATOMIC_RELAXED,
                               __HIP_MEMORY_SCOPE_AGENT);
    }
    return;
  }

  // ================== recurrent role (r12 verbatim + gemm gate) ==========
  int ch = w >> 2;                        // col-half 0..1
  int kw = w & 3;                         // K-quarter 0..3
  int grp = wg >> 4;      // batch rows grp*8..+8
  int slot = wg & 15;     // hidden cols slot*64..+64

  // ---- pinned weights: 3 gates x 2 n-tiles x 8 k-frags = 192 VGPRs ----
  int klane = (lane >> 4) * 8;
  int k0 = kw * 256;
  i32x4 wfi[3][2][8];
#pragma unroll
  for (int g2 = 0; g2 < 3; ++g2)
#pragma unroll
    for (int n2 = 0; n2 < 2; ++n2) {
      int col = slot * 64 + ch * 32 + n2 * 16 + (lane & 15);
      load_frags8(wh + ((long)g2 << 20) + (long)col * 1024 + k0 + klane, wfi[g2][n2]);
    }

  // ---- per-thread pointwise cell: row=tid>>6 (0..7), col=tid&63 ----
  int row = tid >> 6, col = tid & 63;
  long cellofs = (long)(grp * 8 + row) * 1024 + slot * 64 + col;
  float h_local = clampf(state[cellofs]);
  float bnh_v = bnh[slot * 64 + col];

  // ---- t=0 staging from clamp(state): 4 x (4-cell) chunks/thread ----
#pragma unroll
  for (int c = 0; c < 4; ++c) {
    int n = c * 512 + tid;                    // 4-cell chunk id (0..2047)
    int r8 = n >> 8;                          // row 0..7
    int coli = (n * 4) & 1023;
    const float* sp = state + (long)(grp * 8 + r8) * 1024 + coli;
    float4 v = *(const float4*)sp;
    int2 pv;
    pv.x = (int)(f2bf(clampf(v.x)) | ((unsigned)f2bf(clampf(v.y)) << 16));
    pv.y = (int)(f2bf(clampf(v.z)) | ((unsigned)f2bf(clampf(v.w)) << 16));
    int flat = n * 8;
    *(int2*)((char*)h_lds + (flat ^ (r8 << 4))) = pv;
  }

  // ---- LDS fragment read addressing (M=8: rows duplicated, row = lane&7) ----
  const int rowb = (lane & 7) * 2048;
  const int colb = kw * 512 + ((lane >> 4) * 16);
  const int rsw = (lane & 7) << 4;

  // ---- gate on gemm progress for t=0 (bm 0), then load pw inputs ----
  {
    unsigned it = 0;
    while (load_u32_mall(&cnt[0]) < 24u && it < (1u << 17)) {
      ++it;
      __builtin_amdgcn_s_sleep(8);
    }
  }
  float grv, giv, gniv;
  {
    unsigned a, b; float c;
    asm volatile(
        "global_load_ushort %0, %3, off sc0 sc1\n\t"
        "global_load_ushort %1, %4, off sc0 sc1\n\t"
        "global_load_dword %2, %5, off sc0 sc1\n\t"
        "s_waitcnt vmcnt(0)"
        : "=&v"(a), "=&v"(b), "=&v"(c)
        : "v"(gr + cellofs), "v"(gi + cellofs), "v"(out + cellofs)
        : "memory");
    grv = bf2f((unsigned short)a); giv = bf2f((unsigned short)b); gniv = c;
  }
  unsigned wm_done = 1;   // cnt[0] confirmed

  __syncthreads();

#pragma unroll 1
  for (int t = 0; t < NT; ++t) {
    f32x4 acc[3][2] = {};
#pragma unroll
    for (int s = 0; s < 8; ++s) {
      bf16x8 a = *(const bf16x8*)((const char*)h_lds + rowb + ((colb + s * 64) ^ rsw));
#pragma unroll
      for (int g2 = 0; g2 < 3; ++g2)
#pragma unroll
        for (int n2 = 0; n2 < 2; ++n2)
          acc[g2][n2] = __builtin_amdgcn_mfma_f32_16x16x32_bf16(
              a, __builtin_bit_cast(bf16x8, wfi[g2][n2][s]), acc[g2][n2], 0, 0, 0);
    }

    // stage valid C rows (rows 0..7 live in lanes 0..31)
    int rq = lane >> 4;
    if (rq < 2) {
#pragma unroll
      for (int g2 = 0; g2 < 3; ++g2)
#pragma unroll
        for (int n2 = 0; n2 < 2; ++n2)
#pragma unroll
          for (int r = 0; r < 4; ++r)
            red[kw][g2][n2][ch][rq * 4 + r][lane & 15] = acc[g2][n2][r];
    }
    __syncthreads();                                  // B1

    int chc = col >> 5, n2c = (col >> 4) & 1, cc = col & 15;
    float pr = red[0][0][n2c][chc][row][cc] + red[1][0][n2c][chc][row][cc]
             + red[2][0][n2c][chc][row][cc] + red[3][0][n2c][chc][row][cc];
    float pi = red[0][1][n2c][chc][row][cc] + red[1][1][n2c][chc][row][cc]
             + red[2][1][n2c][chc][row][cc] + red[3][1][n2c][chc][row][cc];
    float pn = red[0][2][n2c][chc][row][cc] + red[1][2][n2c][chc][row][cc]
             + red[2][2][n2c][chc][row][cc] + red[3][2][n2c][chc][row][cc];

    float rg = fsigmoid(pr + grv);
    float ig = fsigmoid(pi + giv);
    float ng = ftanh(gniv + clampf(rg * (pn + bnh_v)));
    float sx = clampf(h_local) - ng;
    float hy = ng + clampf(ig * sx);

    unsigned tgt = (unsigned)(t + 1);
    long bank = (long)(tgt & 1) * NBH;
    // publish tagged h(t+1) FIRST (starts the mall RT earliest)
    store_u32_wt(hbuf + bank + cellofs, ((unsigned)f2bf(hy) << 16) | tgt);
    out[(long)t * NBH + cellofs] = hy;
    h_local = hy;

    if (t + 1 < NT) {
      // gate next timestep's gemm outputs (bm = (t+1)>>1), watermark-cached
      unsigned bm_needed = tgt >> 1;
      if (bm_needed >= wm_done) {
        unsigned it = 0;
        while (load_u32_mall(&cnt[bm_needed]) < 24u && it < (1u << 17)) {
          ++it;
          __builtin_amdgcn_s_sleep(8);
        }
        wm_done = bm_needed + 1;
      }

      // issue next step's pw-input loads (no wait; h-poll's vmcnt covers them)
      long g2ofs = (long)tgt * NBH + cellofs;
      unsigned pwa, pwb; float pwc;
      asm volatile(
          "global_load_ushort %0, %3, off sc0 sc1\n\t"
          "global_load_ushort %1, %4, off sc0 sc1\n\t"
          "global_load_dword %2, %5, off sc0 sc1"
          : "=&v"(pwa), "=&v"(pwb), "=&v"(pwc)
          : "v"(gr + g2ofs), "v"(gi + g2ofs), "v"(out + g2ofs)
          : "memory");

      // cooperative full-reload tagged poll: 4 x 16B chunks/thread
      const unsigned int* base = hbuf + bank + (long)grp * 8192;
      i32x4 d[4];
      for (unsigned it2 = 0;; ++it2) {
#pragma unroll
        for (int c = 0; c < 4; ++c) {
          const unsigned int* p = base + (long)(c * 512 + tid) * 4;
          asm volatile("global_load_dwordx4 %0, %1, off sc0 sc1"
                       : "=&v"(d[c]) : "v"(p) : "memory");
        }
        asm volatile("s_waitcnt vmcnt(0)" ::: "memory");
        unsigned mn = 0xFFFFFFFFu;
#pragma unroll
        for (int c = 0; c < 4; ++c)
#pragma unroll
          for (int e = 0; e < 4; ++e)
            mn = min(mn, ((unsigned)d[c][e]) & 0xFFFFu);
        if (__all((int)(mn >= tgt)) || it2 > 8192u) break;
        __builtin_amdgcn_s_sleep(1);
      }
      __builtin_amdgcn_sched_barrier(0);   // pw regs valid after vmcnt(0)
      grv = bf2f((unsigned short)pwa);
      giv = bf2f((unsigned short)pwb);
      gniv = pwc;

      // unpack hi16 -> bf16 pairs, swizzled 8B LDS writes
#pragma unroll
      for (int c = 0; c < 4; ++c) {
        int n = c * 512 + tid;
        int r8 = n >> 8;
        int flat = n * 8;
        int2 v;
        v.x = (int)__builtin_amdgcn_perm((unsigned)d[c][1], (unsigned)d[c][0], 0x07060302u);
        v.y = (int)__builtin_amdgcn_perm((unsigned)d[c][3], (unsigned)d[c][2], 0x07060302u);
        *(int2*)((char*)h_lds + (flat ^ (r8 << 4))) = v;
      }
      __syncthreads();                                // B2: h_lds(t+1) ready
    }
  }

  // last hidden state
  out[(long)NT * NBH + cellofs] = h_local;
}

// ---------------------------------------------------------------------------
extern "C" void kernel_launch(void* const* d_in, const int* in_sizes, int n_in,
                              void* d_out, int out_size, void* d_ws, size_t ws_size,
                              hipStream_t stream) {
  const float* inputs = (const float*)d_in[0];
  const float* state  = (const float*)d_in[1];
  const float* wri = (const float*)d_in[2];
  const float* wii = (const float*)d_in[3];
  const float* wni = (const float*)d_in[4];
  const float* wrh = (const float*)d_in[5];
  const float* wih = (const float*)d_in[6];
  const float* wnh = (const float*)d_in[7];
  const float* br  = (const float*)d_in[8];
  const float* bi  = (const float*)d_in[9];
  const float* bni = (const float*)d_in[10];
  const float* bnh = (const float*)d_in[11];

  if (ws_size < WS_NEED) {
    fprintf(stderr, "kernel_launch: ws too small (%zu < %lu)\n", ws_size, WS_NEED);
    return;
  }

  char* ws = (char*)d_ws;
  unsigned int*   cnt   = (unsigned int*)(ws + OFF_CNT);
  unsigned int*   hbuf  = (unsigned int*)(ws + OFF_HBUF);
  unsigned short* wcat  = (unsigned short*)(ws + OFF_WCAT);
  unsigned short* whp   = (unsigned short*)(ws + OFF_WH);
  unsigned short* grw   = (unsigned short*)(ws + OFF_GR);
  unsigned short* giw   = (unsigned short*)(ws + OFF_GI);
  float* out = (float*)d_out;

  // zero counters + tag region every launch (stale values must die)
  hipMemsetAsync(ws, 0, OFF_WCAT, stream);
  k_convert_weights<<<512, 256, 0, stream>>>(wri, wii, wni, wrh, wih, wnh, wcat, whp);
  k_fused<<<256, 512, 0, stream>>>(whp, wcat, inputs, state, br, bi, bni, bnh,
                                   grw, giw, hbuf, cnt, out);
}